// Round 8
// baseline (254.933 us; speedup 1.0000x reference)
//
#include <hip/hip_runtime.h>

// B=4, T=4096, E=1024, H=64.
// out = Q @ M_b,  M_b = (1/32) * K_b^T V_b,  Q/K/V = idx@W + b   (linear attention:
// reference applies no mask/softmax). Scale folded into Wk/bk.
//
// R15: ABLATION ROUND. R7-R14: six qkv structures all 42-65us, util <10%, FETCH
// ~34MB invariant; three stream-serialization theories refuted (R13 B-bytes,
// R14 ring-depth -> compiler sank loads, VGPR=36). This round isolates the three
// candidate mechanisms as standalone probe dispatches (rocprof gives per-dispatch
// dur) + runs the best verified pipeline (R10) for the scored output:
//   probe_a:     R12's A-pattern (16 lanes x 4KB row stride)    -> strided-read rate
//   probe_a_lin: same volume, fully linear                      -> achievable floor
//   probe_b:     R10's B-pattern (512 blocks broadcast 384KB)   -> L2 broadcast rate
// Whichever probe is slow names the real invariant for R16.

typedef __attribute__((ext_vector_type(8))) short bf16x8;   // 8 bf16 = 4 VGPRs
typedef __attribute__((ext_vector_type(4))) float f32x4;    // MFMA C/D

#define MFMA16(a, b, c) __builtin_amdgcn_mfma_f32_16x16x32_bf16((a), (b), (c), 0, 0, 0)

__device__ __forceinline__ unsigned short f2bf(float f) {
    unsigned int u = __float_as_uint(f);
    u += 0x7fffu + ((u >> 16) & 1u);          // round-to-nearest-even
    return (unsigned short)(u >> 16);
}

// ===========================================================================
// Probes. Each reads idx only (probe_b uses idx's first 384KB as a WB stand-in:
// same size / same broadcast-across-blocks behavior). Sums kept live via
// atomicAdd into a workspace sink that is never part of the output.
// ===========================================================================
__global__ __launch_bounds__(256, 2) void probe_a(const float* __restrict__ idx,
                                                  float* __restrict__ sink) {
    const int lane = threadIdx.x & 63;
    const float* A0 = idx + (size_t)(blockIdx.x * 32 + (lane & 15)) * 1024 + ((lane >> 4) * 8);
    const float* A1 = A0 + 16 * 1024;
    float4 s = {0.f, 0.f, 0.f, 0.f};
    #pragma unroll 8
    for (int kk = 0; kk < 32; kk++) {
        float4 a = *(const float4*)(A0 + kk * 32);
        float4 b = *(const float4*)(A0 + kk * 32 + 4);
        float4 c = *(const float4*)(A1 + kk * 32);
        float4 d = *(const float4*)(A1 + kk * 32 + 4);
        s.x += a.x + b.x; s.y += c.y + d.y; s.z += a.z + c.z; s.w += b.w + d.w;
    }
    float v = s.x + s.y + s.z + s.w;
    if (lane == 0) atomicAdd(sink + 0, v);
}

__global__ __launch_bounds__(256, 2) void probe_a_lin(const float* __restrict__ idx,
                                                      float* __restrict__ sink) {
    const float* src = idx + (size_t)blockIdx.x * 32768;
    float4 s = {0.f, 0.f, 0.f, 0.f};
    #pragma unroll 8
    for (int i = 0; i < 32; i++) {
        float4 v = *(const float4*)(src + (size_t)i * 1024 + threadIdx.x * 4);
        s.x += v.x; s.y += v.y; s.z += v.z; s.w += v.w;
    }
    float v = s.x + s.y + s.z + s.w;
    if ((threadIdx.x & 63) == 0) atomicAdd(sink + 1, v);
}

__global__ __launch_bounds__(256, 2) void probe_b(const float* __restrict__ idxf,
                                                  float* __restrict__ sink) {
    const unsigned short* Wp = (const unsigned short*)idxf;   // 384KB stand-in
    const int lane = threadIdx.x & 63, w = threadIdx.x >> 6;
    uint4 s = {0u, 0u, 0u, 0u};
    #pragma unroll 8
    for (int kk = 0; kk < 32; kk++) {
        const unsigned short* Bp = Wp + (size_t)((kk * 12) * 64 + lane) * 8;
        #pragma unroll
        for (int j = 0; j < 3; j++) {
            uint4 v = *(const uint4*)(Bp + (w + j * 4) * 512);
            s.x += v.x; s.y += v.y; s.z += v.z; s.w += v.w;
        }
    }
    unsigned int u = s.x + s.y + s.z + s.w;
    if (lane == 0) atomicAdd(sink + 2, (float)(u & 0xffff));
}

// ===========================================================================
// Scored pipeline = R10 (verified pass, best total). Unchanged.
// ===========================================================================
__global__ void prep(const float* __restrict__ Wq, const float* __restrict__ Wk,
                     const float* __restrict__ Wv, unsigned short* __restrict__ WB,
                     float* __restrict__ Mf) {
    int t = blockIdx.x * 256 + threadIdx.x;   // 96 blocks -> 24576 chunks
    if (t < 16384) Mf[t] = 0.f;               // 4 * 64 * 64 fp32 accumulator
    int kki = t / 768;
    int rem = t - kki * 768;
    int nt = rem >> 6, lane = rem & 63;
    int n = nt * 16 + (lane & 15);
    int kb = kki * 32 + ((lane >> 4) * 8);
    int mm = n >> 6, h = n & 63;
    const float* W = (mm == 0) ? Wq : (mm == 1) ? Wk : Wv;
    float sc = (mm == 1) ? 0.03125f : 1.0f;
    bf16x8 v;
    #pragma unroll
    for (int j = 0; j < 8; j++) v[j] = (short)f2bf(W[(size_t)(kb + j) * 64 + h] * sc);
    *(bf16x8*)(WB + (size_t)t * 8) = v;
}

__global__ __launch_bounds__(256, 2) void qkv_m(
    const float* __restrict__ idx, const unsigned short* __restrict__ WB,
    const float* __restrict__ bq, const float* __restrict__ bk, const float* __restrict__ bv,
    unsigned short* __restrict__ Q, float* __restrict__ Mf) {
    __shared__ unsigned short As[32 * 1032];   // 66048 B (stage; reused as Lk/Lv)
    __shared__ unsigned short Lq[32 * 68];     // 4352 B
    unsigned short* Lk = As;                   // [64][36] bf16, K local (h-major)
    unsigned short* Lv = As + 64 * 36;         // [64][36] bf16, V local

    const int tid = threadIdx.x, lane = tid & 63, w = tid >> 6;
    const int r0 = blockIdx.x * 32;

    // ---- phase A: stage 8 contiguous rows per wave ----
    {
        const float* src = idx + (size_t)(r0 + w * 8) * 1024;
        #pragma unroll
        for (int batch = 0; batch < 4; batch++) {
            float4 v[8];
            #pragma unroll
            for (int j = 0; j < 8; j++)
                v[j] = *(const float4*)(src + (size_t)(batch * 8 + j) * 256 + lane * 4);
            #pragma unroll
            for (int j = 0; j < 8; j++) {
                int i   = batch * 8 + j;
                int row = w * 8 + (i >> 2);
                int k   = (i & 3) * 256 + lane * 4;
                unsigned int lo = ((unsigned int)f2bf(v[j].y) << 16) | f2bf(v[j].x);
                unsigned int hi = ((unsigned int)f2bf(v[j].w) << 16) | f2bf(v[j].z);
                uint2 p; p.x = lo; p.y = hi;
                *(uint2*)(As + (size_t)row * 1032 + k) = p;
            }
        }
    }
    __syncthreads();

    // ---- phase B: projection MFMA loop ----
    const f32x4 z4 = {0.f, 0.f, 0.f, 0.f};
    f32x4 acc[2][3] = {{z4, z4, z4}, {z4, z4, z4}};
    {
        const unsigned short* a_base0 = As + (size_t)(lane & 15) * 1032 + ((lane >> 4) * 8);
        const unsigned short* a_base1 = a_base0 + 16 * 1032;
        bf16x8 a_c[2], b0[3], b1[3], b2[3];
        a_c[0] = *(const bf16x8*)a_base0;
        a_c[1] = *(const bf16x8*)a_base1;
        {
            const unsigned short* Bp0 = WB + (size_t)(lane * 8);
            const unsigned short* Bp1 = WB + (size_t)(12 * 64 + lane) * 8;
            #pragma unroll
            for (int j = 0; j < 3; j++) {
                b0[j] = *(const bf16x8*)(Bp0 + (w + j * 4) * 512);
                b1[j] = *(const bf16x8*)(Bp1 + (w + j * 4) * 512);
                b2[j] = b1[j];
            }
        }
        for (int kk = 0; kk < 32; kk++) {
            bf16x8 na0 = a_c[0], na1 = a_c[1];
            if (kk < 30) {
                const unsigned short* Bp = WB + (size_t)(((kk + 2) * 12) * 64 + lane) * 8;
                #pragma unroll
                for (int j = 0; j < 3; j++) b2[j] = *(const bf16x8*)(Bp + (w + j * 4) * 512);
            }
            if (kk < 31) {
                na0 = *(const bf16x8*)(a_base0 + (kk + 1) * 32);
                na1 = *(const bf16x8*)(a_base1 + (kk + 1) * 32);
            }
            #pragma unroll
            for (int j = 0; j < 3; j++) {
                acc[0][j] = MFMA16(a_c[0], b0[j], acc[0][j]);
                acc[1][j] = MFMA16(a_c[1], b0[j], acc[1][j]);
            }
            #pragma unroll
            for (int j = 0; j < 3; j++) { b0[j] = b1[j]; b1[j] = b2[j]; }
            a_c[0] = na0; a_c[1] = na1;
        }
    }

    // ---- phase C: bias + write Q/K/V into LDS (As A-reads done -> reuse) ----
    __syncthreads();
    {
        const int h     = w * 16 + (lane & 15);
        const int rbase = (lane >> 4) * 4;
        float bias0 = bq[h], bias1 = bk[h] * 0.03125f, bias2 = bv[h];
        #pragma unroll
        for (int rf = 0; rf < 2; rf++) {
            #pragma unroll
            for (int reg = 0; reg < 4; reg++) {
                int r = rf * 16 + rbase + reg;
                Lq[r * 68 + h] = f2bf(acc[rf][0][reg] + bias0);
                Lk[h * 36 + r] = f2bf(acc[rf][1][reg] + bias1);   // [h][t], pad 36
                Lv[h * 36 + r] = f2bf(acc[rf][2][reg] + bias2);
            }
        }
    }
    __syncthreads();

    // ---- Q to global, coalesced 16B/lane ----
    {
        int qr = tid >> 3, qh = (tid & 7) * 8;
        *(uint4*)(Q + (size_t)(r0 + qr) * 64 + qh) = *(const uint4*)(Lq + qr * 68 + qh);
    }

    // ---- M contribution (K=t=32) + atomicAdd ----
    {
        const int tq = (lane >> 4) * 8;
        bf16x8 a = *(const bf16x8*)&Lk[(16 * w + (lane & 15)) * 36 + tq];
        f32x4 accM[4];
        #pragma unroll
        for (int nt = 0; nt < 4; nt++) {
            bf16x8 bb = *(const bf16x8*)&Lv[(nt * 16 + (lane & 15)) * 36 + tq];
            accM[nt] = MFMA16(a, bb, z4);
        }
        float* P = Mf + (size_t)(r0 >> 12) * 4096;
        const int rowb = 16 * w + (lane >> 4) * 4;
        #pragma unroll
        for (int nt = 0; nt < 4; nt++)
            #pragma unroll
            for (int reg = 0; reg < 4; reg++)
                atomicAdd(&P[(rowb + reg) * 64 + nt * 16 + (lane & 15)], accM[nt][reg]);
    }
}

__global__ __launch_bounds__(256) void qm(
    const unsigned short* __restrict__ Q, const float* __restrict__ Mf,
    float* __restrict__ out) {
    __shared__ unsigned short Lm[64 * 72];
    const int lane = threadIdx.x & 63, wave = threadIdx.x >> 6;
    const int r0 = blockIdx.x * 64;
    const int b  = r0 >> 12;
    {
        const int tt = threadIdx.x;
        int h1 = tt >> 2, h2c = (tt & 3) * 16;
        const float* Mp = Mf + (size_t)b * 4096 + h1 * 64 + h2c;
        float vals[16];
        *(float4*)(vals + 0)  = *(const float4*)(Mp + 0);
        *(float4*)(vals + 4)  = *(const float4*)(Mp + 4);
        *(float4*)(vals + 8)  = *(const float4*)(Mp + 8);
        *(float4*)(vals + 12) = *(const float4*)(Mp + 12);
        #pragma unroll
        for (int u = 0; u < 16; u++) Lm[(h2c + u) * 72 + h1] = f2bf(vals[u]);
    }
    __syncthreads();
    const f32x4 z4 = {0.f, 0.f, 0.f, 0.f};
    f32x4 acc[4] = {z4, z4, z4, z4};
    const int rr = r0 + 16 * wave + (lane & 15);
    const int kq = (lane >> 4) * 8;
    #pragma unroll
    for (int ks = 0; ks < 2; ks++) {
        int k0 = ks * 32;
        bf16x8 a = *(const bf16x8*)&Q[(size_t)rr * 64 + k0 + kq];
        #pragma unroll
        for (int nt = 0; nt < 4; nt++) {
            bf16x8 bb = *(const bf16x8*)&Lm[(size_t)(nt * 16 + (lane & 15)) * 72 + k0 + kq];
            acc[nt] = MFMA16(a, bb, acc[nt]);
        }
    }
    const int rowb = r0 + 16 * wave + (lane >> 4) * 4;
    #pragma unroll
    for (int nt = 0; nt < 4; nt++)
        #pragma unroll
        for (int reg = 0; reg < 4; reg++)
            out[(size_t)(rowb + reg) * 64 + nt * 16 + (lane & 15)] = acc[nt][reg];
}

// ---------------------------------------------------------------------------
// Workspace layout:
//   [0, 384K)        WB
//   [1M, 1M+64K)     Mf (fp32 M accumulator, zeroed by prep)
//   [2M, 4M)         Q
//   [5M, 5M+64)      probe sink
extern "C" void kernel_launch(void* const* d_in, const int* in_sizes, int n_in,
                              void* d_out, int out_size, void* d_ws, size_t ws_size,
                              hipStream_t stream) {
    const float* idx = (const float*)d_in[0];
    const float* Wq  = (const float*)d_in[1];
    const float* bq  = (const float*)d_in[2];
    const float* Wk  = (const float*)d_in[3];
    const float* bk  = (const float*)d_in[4];
    const float* Wv  = (const float*)d_in[5];
    const float* bv  = (const float*)d_in[6];
    float* out = (float*)d_out;

    char* ws = (char*)d_ws;
    unsigned short* WB   = (unsigned short*)(ws);
    float*          Mf   = (float*)(ws + (1024u << 10));
    unsigned short* Q    = (unsigned short*)(ws + (2048u << 10));
    float*          sink = (float*)(ws + (5120u << 10));

    // ---- ablation probes (isolated per-dispatch durations via rocprof) ----
    hipLaunchKernelGGL(probe_a,     dim3(512), dim3(256), 0, stream, idx, sink);
    hipLaunchKernelGGL(probe_a_lin, dim3(512), dim3(256), 0, stream, idx, sink);
    hipLaunchKernelGGL(probe_b,     dim3(512), dim3(256), 0, stream, idx, sink);

    // ---- scored pipeline (R10) ----
    hipLaunchKernelGGL(prep,  dim3(96),  dim3(256), 0, stream, Wq, Wk, Wv, WB, Mf);
    hipLaunchKernelGGL(qkv_m, dim3(512), dim3(256), 0, stream,
                       idx, WB, bq, bk, bv, Q, Mf);
    hipLaunchKernelGGL(qm,    dim3(256), dim3(256), 0, stream, Q, Mf, out);
}

// Round 9
// 123.403 us; speedup vs baseline: 2.0659x; 2.0659x over previous
//
#include <hip/hip_runtime.h>

// B=4, T=4096, E=1024, H=64.
// out = Q @ M_b,  M_b = (1/32) * K_b^T V_b,  Q/K/V = idx@W + b   (linear attention:
// reference applies no mask/softmax). Scale folded into Wk/bk.
//
// R16: ablation verdict (R15): strided A-direct = 500 GB/s (probe_a 67us) and the
// 512-block broadcast of the 384KB weight table ~= 45us (probe_b, = R10's 42us).
// Fixes: A linear-staged only; BM=64/grid 256 (halve broadcast requests); WB
// replicated x4, block reads copy (bid>>3)&3 (spreads same-XCD blocks over
// distinct line sets -> ~4x less same-line contention). 1024 thr (16 waves:
// wr=w>>2 row-frag, wc=w&3 col-frag), 132KB LDS, 1 block/CU. Tail = R13's.

typedef __attribute__((ext_vector_type(8))) short bf16x8;   // 8 bf16 = 4 VGPRs
typedef __attribute__((ext_vector_type(4))) float f32x4;    // MFMA C/D

#define MFMA16(a, b, c) __builtin_amdgcn_mfma_f32_16x16x32_bf16((a), (b), (c), 0, 0, 0)

__device__ __forceinline__ unsigned short f2bf(float f) {
    unsigned int u = __float_as_uint(f);
    u += 0x7fffu + ((u >> 16) & 1u);          // round-to-nearest-even
    return (unsigned short)(u >> 16);
}

// ---------------------------------------------------------------------------
// K0: weights -> MFMA-fragment order, x4 replicated; zero Mf (ws poisoned).
// Chunk t = (kk*12 + nt)*64 + lane holds 8 bf16:
//   W^T[n][k], n = nt*16 + (lane&15), k = kk*32 + (lane>>4)*8 + j.
// n<64 -> Wq, n<128 -> Wk * 1/32, else Wv.   (W is [k][h] in memory)
__global__ void prep(const float* __restrict__ Wq, const float* __restrict__ Wk,
                     const float* __restrict__ Wv, unsigned short* __restrict__ WB,
                     float* __restrict__ Mf) {
    int t = blockIdx.x * 256 + threadIdx.x;   // 96 blocks -> 24576 chunks
    if (t < 16384) Mf[t] = 0.f;               // 4 * 64 * 64 fp32 accumulator
    int kki = t / 768;
    int rem = t - kki * 768;
    int nt = rem >> 6, lane = rem & 63;
    int n = nt * 16 + (lane & 15);
    int kb = kki * 32 + ((lane >> 4) * 8);
    int mm = n >> 6, h = n & 63;
    const float* W = (mm == 0) ? Wq : (mm == 1) ? Wk : Wv;
    float sc = (mm == 1) ? 0.03125f : 1.0f;
    bf16x8 v;
    #pragma unroll
    for (int j = 0; j < 8; j++) v[j] = (short)f2bf(W[(size_t)(kb + j) * 64 + h] * sc);
    #pragma unroll
    for (int c = 0; c < 4; c++)
        *(bf16x8*)(WB + (size_t)c * 196608 + (size_t)t * 8) = v;
}

// ---------------------------------------------------------------------------
// K1: fused QKV projection + local K^T V contribution.
// Grid 256 x 1024 threads. Stage: wave w linearly loads rows [4w,4w+4) (16KB)
// into As (stride 1032 -> benign banks). Compute: wave (wr,wc): per kk one A
// ds_read_b128 (1 ahead) + 3 B 1KB loads from its WB copy (2-deep register
// pipeline) + 3 MFMAs. Tail: Q coalesced out via LDS; M-tile (K=t=64, 2 MFMAs)
// -> atomicAdd into Mf.
__global__ __launch_bounds__(1024, 4) void qkv_m(
    const float* __restrict__ idx, const unsigned short* __restrict__ WB,
    const float* __restrict__ bq, const float* __restrict__ bk, const float* __restrict__ bv,
    unsigned short* __restrict__ Q, float* __restrict__ Mf) {
    __shared__ unsigned short As[64 * 1032];   // 132096 B; tail reuses as Lq/Lk/Lv

    const int tid = threadIdx.x, lane = tid & 63, w = tid >> 6;
    const int wr = w >> 2, wc = w & 3;
    const int r0 = blockIdx.x * 64;

    // ---- stage: 4 contiguous rows per wave (linear pattern: probe_a_lin) ----
    {
        const float* src = idx + (size_t)(r0 + w * 4) * 1024;
        #pragma unroll
        for (int batch = 0; batch < 2; batch++) {
            float4 v[8];
            #pragma unroll
            for (int j = 0; j < 8; j++)
                v[j] = *(const float4*)(src + (size_t)(batch * 8 + j) * 256 + lane * 4);
            #pragma unroll
            for (int j = 0; j < 8; j++) {
                int i   = batch * 8 + j;
                int row = w * 4 + (i >> 2);            // 4 chunks of 256 floats/row
                int k   = (i & 3) * 256 + lane * 4;
                unsigned int lo = ((unsigned int)f2bf(v[j].y) << 16) | f2bf(v[j].x);
                unsigned int hi = ((unsigned int)f2bf(v[j].w) << 16) | f2bf(v[j].z);
                uint2 p; p.x = lo; p.y = hi;
                *(uint2*)(As + (size_t)row * 1032 + k) = p;
            }
        }
    }
    __syncthreads();

    // ---- compute: B 2-deep register pipeline from this block's WB copy ----
    const f32x4 z4 = {0.f, 0.f, 0.f, 0.f};
    f32x4 acc[3] = {z4, z4, z4};
    {
        const unsigned short* WBc = WB + (size_t)((blockIdx.x >> 3) & 3) * 196608;
        const unsigned short* a_base =
            As + (size_t)(wr * 16 + (lane & 15)) * 1032 + ((lane >> 4) * 8);
        bf16x8 a_c = *(const bf16x8*)a_base;
        bf16x8 b0[3], b1[3], b2[3];
        {
            const unsigned short* Bp0 = WBc + (size_t)(lane * 8);
            const unsigned short* Bp1 = WBc + (size_t)(12 * 64 + lane) * 8;
            #pragma unroll
            for (int j = 0; j < 3; j++) {
                b0[j] = *(const bf16x8*)(Bp0 + (wc + j * 4) * 512);
                b1[j] = *(const bf16x8*)(Bp1 + (wc + j * 4) * 512);
                b2[j] = b1[j];
            }
        }
        for (int kk = 0; kk < 32; kk++) {
            bf16x8 na = a_c;
            if (kk < 30) {
                const unsigned short* Bp = WBc + (size_t)(((kk + 2) * 12) * 64 + lane) * 8;
                #pragma unroll
                for (int j = 0; j < 3; j++) b2[j] = *(const bf16x8*)(Bp + (wc + j * 4) * 512);
            }
            if (kk < 31) na = *(const bf16x8*)(a_base + (kk + 1) * 32);
            #pragma unroll
            for (int j = 0; j < 3; j++) acc[j] = MFMA16(a_c, b0[j], acc[j]);
            #pragma unroll
            for (int j = 0; j < 3; j++) { b0[j] = b1[j]; b1[j] = b2[j]; }
            a_c = na;
        }
    }

    // ---- tail: reuse As as Lq/Lk/Lv [64][72] (16B-aligned rows) ----
    __syncthreads();                              // all A ds_reads done
    unsigned short* Lq = As;
    unsigned short* Lk = As + 4608;
    unsigned short* Lv = As + 9216;
    {
        const int col   = wc * 16 + (lane & 15);
        const int rbase = wr * 16 + (lane >> 4) * 4;
        float b0v = bq[col], b1v = bk[col] * 0.03125f, b2v = bv[col];
        #pragma unroll
        for (int reg = 0; reg < 4; reg++) {
            int r = rbase + reg;
            Lq[r * 72 + col] = f2bf(acc[0][reg] + b0v);
            Lk[col * 72 + r] = f2bf(acc[1][reg] + b1v);   // [h][t]
            Lv[col * 72 + r] = f2bf(acc[2][reg] + b2v);
        }
    }
    __syncthreads();

    // Q out: 64 rows x 64 cols bf16; thread -> (row = tid>>4, 4 cols)
    {
        int row = tid >> 4, c4 = (tid & 15) * 4;
        *(uint2*)(Q + (size_t)(r0 + row) * 64 + c4) = *(const uint2*)(Lq + row * 72 + c4);
    }

    // M contribution: wave (wr,wc) owns the (h1-frag wr, h2-frag wc) 16x16 tile;
    // K = t = 64 via two 16x16x32 MFMAs.
    {
        f32x4 accM = z4;
        #pragma unroll
        for (int ts = 0; ts < 64; ts += 32) {
            bf16x8 ka = *(const bf16x8*)(Lk + (wr * 16 + (lane & 15)) * 72 + ts + (lane >> 4) * 8);
            bf16x8 vb = *(const bf16x8*)(Lv + (wc * 16 + (lane & 15)) * 72 + ts + (lane >> 4) * 8);
            accM = MFMA16(ka, vb, accM);
        }
        float* P = Mf + (size_t)(r0 >> 12) * 4096;
        const int rowb = wr * 16 + (lane >> 4) * 4;
        #pragma unroll
        for (int reg = 0; reg < 4; reg++)
            atomicAdd(&P[(rowb + reg) * 64 + wc * 16 + (lane & 15)], accM[reg]);
    }
}

// ---------------------------------------------------------------------------
// K2: out[r][h2] = Q[r][:] @ M_b[:, h2], fp32 out. M converted fp32->bf16
// fragments in LDS (transposed [h2][h1], stride 72: 2-way banks, free).
__global__ __launch_bounds__(256) void qm(
    const unsigned short* __restrict__ Q, const float* __restrict__ Mf,
    float* __restrict__ out) {
    __shared__ unsigned short Lm[64 * 72];
    const int lane = threadIdx.x & 63, wave = threadIdx.x >> 6;
    const int r0 = blockIdx.x * 64;
    const int b  = r0 >> 12;
    {
        const int tt = threadIdx.x;
        int h1 = tt >> 2, h2c = (tt & 3) * 16;
        const float* Mp = Mf + (size_t)b * 4096 + h1 * 64 + h2c;
        float vals[16];
        *(float4*)(vals + 0)  = *(const float4*)(Mp + 0);
        *(float4*)(vals + 4)  = *(const float4*)(Mp + 4);
        *(float4*)(vals + 8)  = *(const float4*)(Mp + 8);
        *(float4*)(vals + 12) = *(const float4*)(Mp + 12);
        #pragma unroll
        for (int u = 0; u < 16; u++) Lm[(h2c + u) * 72 + h1] = f2bf(vals[u]);
    }
    __syncthreads();
    const f32x4 z4 = {0.f, 0.f, 0.f, 0.f};
    f32x4 acc[4] = {z4, z4, z4, z4};
    const int rr = r0 + 16 * wave + (lane & 15);
    const int kq = (lane >> 4) * 8;
    #pragma unroll
    for (int ks = 0; ks < 2; ks++) {
        int k0 = ks * 32;
        bf16x8 a = *(const bf16x8*)&Q[(size_t)rr * 64 + k0 + kq];
        #pragma unroll
        for (int nt = 0; nt < 4; nt++) {
            bf16x8 bb = *(const bf16x8*)&Lm[(size_t)(nt * 16 + (lane & 15)) * 72 + k0 + kq];
            acc[nt] = MFMA16(a, bb, acc[nt]);
        }
    }
    const int rowb = r0 + 16 * wave + (lane >> 4) * 4;
    #pragma unroll
    for (int nt = 0; nt < 4; nt++)
        #pragma unroll
        for (int reg = 0; reg < 4; reg++)
            out[(size_t)(rowb + reg) * 64 + nt * 16 + (lane & 15)] = acc[nt][reg];
}

// ---------------------------------------------------------------------------
// Workspace layout:
//   [0, 1.5M)        WB x4 copies (384K each)
//   [2M, 2M+64K)     Mf (fp32 M accumulator, zeroed by prep)
//   [3M, 5M)         Q
extern "C" void kernel_launch(void* const* d_in, const int* in_sizes, int n_in,
                              void* d_out, int out_size, void* d_ws, size_t ws_size,
                              hipStream_t stream) {
    const float* idx = (const float*)d_in[0];
    const float* Wq  = (const float*)d_in[1];
    const float* bq  = (const float*)d_in[2];
    const float* Wk  = (const float*)d_in[3];
    const float* bk  = (const float*)d_in[4];
    const float* Wv  = (const float*)d_in[5];
    const float* bv  = (const float*)d_in[6];
    float* out = (float*)d_out;

    char* ws = (char*)d_ws;
    unsigned short* WB = (unsigned short*)(ws);
    float*          Mf = (float*)(ws + (2048u << 10));
    unsigned short* Q  = (unsigned short*)(ws + (3072u << 10));

    hipLaunchKernelGGL(prep,  dim3(96),  dim3(256),  0, stream, Wq, Wk, Wv, WB, Mf);
    hipLaunchKernelGGL(qkv_m, dim3(256), dim3(1024), 0, stream,
                       idx, WB, bq, bk, bv, Q, Mf);
    hipLaunchKernelGGL(qm,    dim3(256), dim3(256),  0, stream, Q, Mf, out);
}